// Round 2
// baseline (3811.464 us; speedup 1.0000x reference)
//
// NeRTModel_60997125538302 — round 2: f32 I/O fix (round 1 misread f32 inputs as bf16 -> NaN).
// All float tensors are float32; seq_lens int32; out float32.
// bf16 conversion happens in-workspace (k0) / at LDS staging, for MFMA use only.
// Pipeline: k0 cvt -> k1 pool(2 news/blk, MFMA qk) -> k3 xW(MFMA, bf16 out) -> k2 x2p
//           -> k4 lstm(4 blocks: dir x batchgroup16, W_hh in regs) -> k4b fill
//           -> k5 causal online softmax (query term cancels) -> k6 out MLP + mask.
// ws usage ~68MB.

#include <hip/hip_runtime.h>
#include <hip/hip_bf16.h>
#include <cstdint>
#include <cstddef>

typedef unsigned short u16;
typedef __attribute__((ext_vector_type(8))) short short8v;
typedef __attribute__((ext_vector_type(4))) short short4v;
typedef __attribute__((ext_vector_type(4))) float f32x4;

#define MFMA16 __builtin_amdgcn_mfma_f32_16x16x32_bf16

__device__ __forceinline__ float bf2f(u16 u){
  union { unsigned int i; float f; } v; v.i = ((unsigned int)u) << 16; return v.f;
}
__device__ __forceinline__ u16 f2bf(float f){
  union { float f; unsigned int u; } v; v.f = f;
  unsigned int r = v.u + 0x7FFFu + ((v.u >> 16) & 1u);
  return (u16)(r >> 16);
}
__device__ __forceinline__ short8v szero(){
  short8v z;
  #pragma unroll
  for (int i = 0; i < 8; i++) z[i] = 0;
  return z;
}
__device__ __forceinline__ float sigm(float x){ return 1.0f/(1.0f + __expf(-x)); }
__device__ __forceinline__ float tanh_u(float x){
  float e = __expf(2.f*x);              // overflow -> inf -> tanh=1 (graceful, no NaN)
  return 1.f - 2.f/(e + 1.f);
}

// ---------------- K0: convert weights f32 -> bf16 in ws; fuse LSTM biases ----------------
__global__ void k0_cvt(const float* __restrict__ wq, const float* __restrict__ wk,
                       const float* __restrict__ wihf, const float* __restrict__ wihb,
                       const float* __restrict__ whhf, const float* __restrict__ whhb,
                       const float* __restrict__ bihf, const float* __restrict__ bhhf,
                       const float* __restrict__ bihb, const float* __restrict__ bhhb,
                       u16* __restrict__ wqb, u16* __restrict__ wkb,
                       u16* __restrict__ wihfb, u16* __restrict__ wihbb,
                       u16* __restrict__ whhfb, u16* __restrict__ whhbb,
                       float* __restrict__ bgf, float* __restrict__ bgb){
  int i = blockIdx.x*256 + threadIdx.x;
  if (i < 160000){
    wqb[i] = f2bf(wq[i]); wkb[i] = f2bf(wk[i]);
    whhfb[i] = f2bf(whhf[i]); whhbb[i] = f2bf(whhb[i]);
  }
  if (i < 320000){ wihfb[i] = f2bf(wihf[i]); wihbb[i] = f2bf(wihb[i]); }
  if (i < 800){ bgf[i] = bihf[i] + bhhf[i]; bgb[i] = bihb[i] + bhhb[i]; }
}

// ---------------- K1: per-news word-attention pooling (2 news per block) ----------------
__launch_bounds__(256)
__global__ void k1_pool(const float* __restrict__ x2,
                        const u16* __restrict__ wqb, const float* __restrict__ bq,
                        const u16* __restrict__ wkb, const float* __restrict__ bk,
                        float* __restrict__ pooled){
  __shared__ u16 tok[2][6400];
  __shared__ u16 qs [2][6400];
  __shared__ u16 kss[2][6400];
  __shared__ u16 probs[2][5120];
  __shared__ float msum[2][256];
  __shared__ float tval[2][16];
  __shared__ float attw[2][16];
  const int tid = threadIdx.x;
  const size_t n0 = (size_t)blockIdx.x * 2;
  const float* src = x2 + n0*6400;
  for (int i = tid; i < 3200; i += 256){
    f32x4 v = *(const f32x4*)&src[(size_t)i*4];
    short4v s; s[0]=f2bf(v[0]); s[1]=f2bf(v[1]); s[2]=f2bf(v[2]); s[3]=f2bf(v[3]);
    int j = i / 1600, r = i - j*1600;
    ((short4v*)tok[j])[r] = s;
  }
  __syncthreads();

  const int lane = tid & 63, wv = tid >> 6;
  const int q = lane & 15, kg = lane >> 4;
  {
    const int proj = wv >> 1;                 // 0: q, 1: k
    const int ntbase = (wv & 1) ? 13 : 0;
    const int ntcnt  = (wv & 1) ? 12 : 13;    // 25 col-tiles total
    const u16* W    = proj ? wkb : wqb;
    const float* bias = proj ? bk : bq;
    short8v A[2][13];
    #pragma unroll
    for (int j = 0; j < 2; j++)
      #pragma unroll
      for (int ksi = 0; ksi < 13; ksi++){
        int e0 = ksi*32 + kg*8;
        A[j][ksi] = (e0 < 400) ? *(const short8v*)&tok[j][q*400 + e0] : szero();
      }
    u16* d0 = proj ? kss[0] : qs[0];
    u16* d1 = proj ? kss[1] : qs[1];
    for (int ti = 0; ti < ntcnt; ti++){
      int col = (ntbase + ti)*16 + q;
      float bv = bias[col];
      f32x4 acc0, acc1;
      acc0[0]=bv; acc0[1]=bv; acc0[2]=bv; acc0[3]=bv; acc1 = acc0;
      const u16* wrow = W + (size_t)col*400;
      #pragma unroll
      for (int ksi = 0; ksi < 13; ksi++){
        int e0 = ksi*32 + kg*8;
        short8v bf = (e0 < 400) ? *(const short8v*)&wrow[e0] : szero();
        acc0 = MFMA16(A[0][ksi], bf, acc0, 0, 0, 0);
        acc1 = MFMA16(A[1][ksi], bf, acc1, 0, 0, 0);
      }
      #pragma unroll
      for (int r = 0; r < 4; r++){          // D: row=(l>>4)*4+r, col=l&15
        d0[(kg*4+r)*400 + col] = f2bf(acc0[r]);
        d1[(kg*4+r)*400 + col] = f2bf(acc1[r]);
      }
    }
  }
  __syncthreads();
  // scores per (news, head, sq): dot20 over head dims, softmax over sk
  for (int r0 = tid; r0 < 640; r0 += 256){
    int j = r0 / 320, rem = r0 - j*320;
    int hh = rem >> 4, sq = rem & 15;
    const u16* qrow = &qs[j][sq*400 + hh*20];
    float qv[20];
    #pragma unroll
    for (int d5 = 0; d5 < 5; d5++){
      short4v v = *(const short4v*)&qrow[d5*4];
      qv[d5*4+0]=bf2f((u16)v[0]); qv[d5*4+1]=bf2f((u16)v[1]);
      qv[d5*4+2]=bf2f((u16)v[2]); qv[d5*4+3]=bf2f((u16)v[3]);
    }
    float sc[16]; float mx = -1e30f;
    #pragma unroll
    for (int sk = 0; sk < 16; sk++){
      const u16* krow = &kss[j][sk*400 + hh*20];
      float s = 0.f;
      #pragma unroll
      for (int d5 = 0; d5 < 5; d5++){
        short4v v = *(const short4v*)&krow[d5*4];
        s += qv[d5*4+0]*bf2f((u16)v[0]) + qv[d5*4+1]*bf2f((u16)v[1])
           + qv[d5*4+2]*bf2f((u16)v[2]) + qv[d5*4+3]*bf2f((u16)v[3]);
      }
      s *= 0.22360679775f;                   // 1/sqrt(20)
      sc[sk] = s; mx = fmaxf(mx, s);
    }
    float sum = 0.f;
    #pragma unroll
    for (int sk = 0; sk < 16; sk++){ sc[sk] = __expf(sc[sk]-mx); sum += sc[sk]; }
    float inv = 1.f/sum;
    #pragma unroll
    for (int sk = 0; sk < 16; sk++) probs[j][(hh*16+sq)*16 + sk] = f2bf(sc[sk]*inv);
  }
  __syncthreads();
  #pragma unroll
  for (int it = 0; it < 2; it++){            // mean over heads
    int idx = tid + it*256;
    int j = idx >> 8, sq = (idx >> 4) & 15, sk = idx & 15;
    float s = 0.f;
    #pragma unroll
    for (int hh = 0; hh < 20; hh++) s += bf2f(probs[j][(hh*16+sq)*16 + sk]);
    msum[j][sq*16+sk] = s * 0.05f;
  }
  __syncthreads();
  if (tid < 32){                             // mean over sk
    int j = tid >> 4, sq = tid & 15;
    float s = 0.f;
    #pragma unroll
    for (int sk = 0; sk < 16; sk++) s += msum[j][sq*16+sk];
    tval[j][sq] = s * 0.0625f;
  }
  __syncthreads();
  if (tid < 2){                              // softmax over sq (16 values)
    float mx = -1e30f;
    for (int i = 0; i < 16; i++) mx = fmaxf(mx, tval[tid][i]);
    float sum = 0.f; float ev[16];
    for (int i = 0; i < 16; i++){ ev[i] = __expf(tval[tid][i]-mx); sum += ev[i]; }
    float inv = 1.f/sum;
    for (int i = 0; i < 16; i++) attw[tid][i] = ev[i]*inv;
  }
  __syncthreads();
  for (int e = tid; e < 800; e += 256){
    int j = e / 400, c = e - j*400;
    float acc = 0.f;
    #pragma unroll
    for (int s = 0; s < 16; s++) acc += attw[j][s]*bf2f(tok[j][s*400 + c]);
    pooled[(n0+j)*400 + c] = acc;
  }
}

// ---------------- K2: x2p = pooled @ w_mlp_mha^T + b (f32 VALU) ----------------
__global__ void k2_x2p(const float* __restrict__ pooled, const float* __restrict__ wmha,
                       const float* __restrict__ bmha, float* __restrict__ x2p){
  __shared__ float rows[3200];
  const int tid = threadIdx.x;
  const size_t n0 = (size_t)blockIdx.x*8;
  for (int i = tid; i < 3200; i += 256) rows[i] = pooled[n0*400 + i];
  __syncthreads();
  for (int j = tid; j < 400; j += 256){
    float bv = bmha[j];
    float acc[8];
    #pragma unroll
    for (int r = 0; r < 8; r++) acc[r] = bv;
    const float* wr = wmha + (size_t)j*400;
    for (int e = 0; e < 400; e += 4){
      const f32x4 w4 = *(const f32x4*)&wr[e];
      #pragma unroll
      for (int r = 0; r < 8; r++){
        const f32x4 x4 = *(const f32x4*)&rows[r*400 + e];
        acc[r] += x4[0]*w4[0] + x4[1]*w4[1] + x4[2]*w4[2] + x4[3]*w4[3];
      }
    }
    #pragma unroll
    for (int r = 0; r < 8; r++) x2p[(n0+r)*400 + j] = acc[r];
  }
}

// ---------------- K3: xW[t][b][hu][gate] = x @ W_ih^T + (b_ih+b_hh), bf16 out ----------------
__launch_bounds__(512)
__global__ void k3_xw(const float* __restrict__ x1, const int* __restrict__ seq,
                      const u16* __restrict__ wihfb, const u16* __restrict__ wihbb,
                      const float* __restrict__ bgf, const float* __restrict__ bgb,
                      u16* __restrict__ xWf, u16* __restrict__ xWb){
  __shared__ u16 xf[12800];
  __shared__ u16 xb[12800];
  const int tid = threadIdx.x;
  const int t = blockIdx.x;
  for (int i = tid; i < 3200; i += 512){
    int b = i / 100, e4 = i - b*100;
    f32x4 vf = *(const f32x4*)&x1[((size_t)b*256 + t)*400 + e4*4];
    int rb = seq[b] - 1 - t; if (rb < 0) rb = 0;     // clip(L-1-t, 0, T-1)
    f32x4 vb = *(const f32x4*)&x1[((size_t)b*256 + rb)*400 + e4*4];
    short4v sf, sb;
    #pragma unroll
    for (int r = 0; r < 4; r++){ sf[r] = f2bf(vf[r]); sb[r] = f2bf(vb[r]); }
    ((short4v*)xf)[i] = sf;
    ((short4v*)xb)[i] = sb;
  }
  __syncthreads();
  const int lane = tid & 63, wv = tid >> 6;
  const int dir = wv >> 2, wl = wv & 3;
  const u16* xs = dir ? xb : xf;
  const u16* W  = dir ? wihbb : wihfb;
  const float* bg = dir ? bgb : bgf;
  u16* xW = dir ? xWb : xWf;
  const int q = lane & 15, kg = lane >> 4;
  short8v A[2][13];
  #pragma unroll
  for (int mt = 0; mt < 2; mt++)
    #pragma unroll
    for (int ksi = 0; ksi < 13; ksi++){
      int e0 = ksi*32 + kg*8;
      A[mt][ksi] = (e0 < 400) ? *(const short8v*)&xs[(mt*16 + q)*400 + e0] : szero();
    }
  for (int nt = wl; nt < 50; nt += 4){
    int g = nt*16 + q;                       // gate row 0..799 (i,f,g,o blocks of 200)
    float bv = bg[g];
    f32x4 acc0, acc1;
    acc0[0]=bv; acc0[1]=bv; acc0[2]=bv; acc0[3]=bv; acc1 = acc0;
    const u16* wrow = W + (size_t)g*400;
    #pragma unroll
    for (int ksi = 0; ksi < 13; ksi++){
      int e0 = ksi*32 + kg*8;
      short8v bf = (e0 < 400) ? *(const short8v*)&wrow[e0] : szero();
      acc0 = MFMA16(A[0][ksi], bf, acc0, 0,0,0);
      acc1 = MFMA16(A[1][ksi], bf, acc1, 0,0,0);
    }
    int gt = g / 200, hu = g - gt*200;
    #pragma unroll
    for (int r = 0; r < 4; r++){
      int b0 = kg*4 + r;
      xW[(((size_t)t*32 +      b0)*200 + hu)*4 + gt] = f2bf(acc0[r]);
      xW[(((size_t)t*32 + 16 + b0)*200 + hu)*4 + gt] = f2bf(acc1[r]);
    }
  }
}

// ---------------- K4: sequential BiLSTM. grid 4 = (dir, batch group of 16). ----------------
// block 256 (4 waves); wave wv owns gate-type wv (200 cols = 13 padded tiles), W_hh in regs.
__launch_bounds__(256, 1)
__global__ void k4_lstm(const u16* __restrict__ xWf, const u16* __restrict__ xWb,
                        const u16* __restrict__ whhfb, const u16* __restrict__ whhbb,
                        const int* __restrict__ seq, float* __restrict__ h_ws){
  __shared__ u16 h_lds[16*200];            // h_{t-1}, bf16
  __shared__ u16 gates[16*200*4];          // [b][hu][gate] bf16
  __shared__ int Ls[16];
  const int tid = threadIdx.x;
  const int dir = blockIdx.x >> 1, grp = blockIdx.x & 1;
  const u16* xW  = dir ? xWb : xWf;
  const u16* whh = dir ? whhbb : whhfb;
  if (tid < 16) Ls[tid] = seq[grp*16 + tid];
  for (int i = tid; i < 3200; i += 256) h_lds[i] = 0;
  const int lane = tid & 63, wv = tid >> 6;      // wv = gate type (i,f,g,o)
  const int q = lane & 15, kg = lane >> 4;
  short8v Bf[13][7];                             // resident W_hh slice (364 VGPRs)
  #pragma unroll
  for (int nt = 0; nt < 13; nt++){
    int cl = nt*16 + q;                          // hidden-unit col (pad >=200)
    #pragma unroll
    for (int ksi = 0; ksi < 7; ksi++){
      int k0 = ksi*32 + kg*8;
      Bf[nt][ksi] = (cl < 200 && k0 < 200)
        ? *(const short8v*)&whh[(size_t)(wv*200 + cl)*200 + k0] : szero();
    }
  }
  float cst[13];
  #pragma unroll
  for (int i = 0; i < 13; i++) cst[i] = 0.f;
  __syncthreads();
  #pragma unroll 1
  for (int t = 0; t < 256; t++){
    // prefetch xW[t] for my cells (hidden under the MFMA phase)
    short4v xwv[13];
    #pragma unroll
    for (int i = 0; i < 13; i++){
      int p = tid + i*256;
      if (p < 3200){
        int b = p / 200, hu = p - b*200;
        xwv[i] = *(const short4v*)&xW[(((size_t)t*32 + grp*16 + b)*200 + hu)*4];
      }
    }
    // MFMA: gates = h_{t-1} @ W_hh^T (wave's 200-col slice)
    f32x4 acc[13];
    #pragma unroll
    for (int nt = 0; nt < 13; nt++){ acc[nt][0]=0.f; acc[nt][1]=0.f; acc[nt][2]=0.f; acc[nt][3]=0.f; }
    #pragma unroll
    for (int ksi = 0; ksi < 7; ksi++){
      int k0 = ksi*32 + kg*8;
      short8v a = (k0 < 200) ? *(const short8v*)&h_lds[q*200 + k0] : szero();
      #pragma unroll
      for (int nt = 0; nt < 13; nt++)
        acc[nt] = MFMA16(a, Bf[nt][ksi], acc[nt], 0,0,0);
    }
    #pragma unroll
    for (int nt = 0; nt < 13; nt++){
      int cl = nt*16 + q;
      if (cl < 200){
        #pragma unroll
        for (int r = 0; r < 4; r++)
          gates[((kg*4 + r)*200 + cl)*4 + wv] = f2bf(acc[nt][r]);
      }
    }
    __syncthreads();
    // activation: 3200 cells / 256 threads (13th iter partial)
    #pragma unroll
    for (int i = 0; i < 13; i++){
      int p = tid + i*256;
      if (p < 3200){
        int b = p / 200, hu = p - b*200;
        short4v g4 = *(const short4v*)&gates[(size_t)p*4];
        float gi = bf2f((u16)g4[0]) + bf2f((u16)xwv[i][0]);
        float gf = bf2f((u16)g4[1]) + bf2f((u16)xwv[i][1]);
        float gg = bf2f((u16)g4[2]) + bf2f((u16)xwv[i][2]);
        float go = bf2f((u16)g4[3]) + bf2f((u16)xwv[i][3]);
        float c = sigm(gf)*cst[i] + sigm(gi)*tanh_u(gg);
        cst[i] = c;
        float hv = sigm(go)*tanh_u(c);
        h_lds[p] = f2bf(hv);
        int gb = grp*16 + b;
        if (dir == 0){
          h_ws[((size_t)gb*256 + t)*400 + hu] = hv;
        } else {
          int tp = Ls[b] - 1 - t;            // un-reverse at store time
          if (tp >= 0) h_ws[((size_t)gb*256 + tp)*400 + 200 + hu] = hv;
        }
      }
    }
    __syncthreads();
  }
}

// ---------------- K4b: fill bwd rows t>=L with h_bwd_r[0] (== stored row L-1) ----------------
__global__ void k4b_fill(const int* __restrict__ seq, float* __restrict__ h_ws){
  const int b = blockIdx.x;
  const int L = seq[b];
  const int cnt = (256 - L)*200;
  const float* src = h_ws + ((size_t)b*256 + (L-1))*400 + 200;
  for (int i = threadIdx.x; i < cnt; i += 256){
    int tt = L + i/200, cc = i - (i/200)*200;
    h_ws[((size_t)b*256 + tt)*400 + 200 + cc] = src[cc];
  }
}

// ---------------- K5: causal growing-window attention (query term cancels) ----------------
__launch_bounds__(512)
__global__ void k5_attn(const float* __restrict__ h_ws, const float* __restrict__ wattn,
                        float* __restrict__ x1_att){
  __shared__ float a_lds[256];
  const int tid = threadIdx.x;
  const int b = blockIdx.x;
  const int lane = tid & 63, wv = tid >> 6;
  for (int row = wv*32; row < wv*32 + 32; row++){
    float s = 0.f;
    for (int j = lane; j < 400; j += 64)
      s += h_ws[((size_t)b*256 + row)*400 + j] * wattn[j];
    #pragma unroll
    for (int m = 32; m > 0; m >>= 1) s += __shfl_xor(s, m, 64);
    if (lane == 0) a_lds[row] = s;
  }
  __syncthreads();
  const int col = tid;
  const bool act = col < 400;
  float m = -1e30f, den = 0.f, num = 0.f;
  const float* hb = h_ws + (size_t)b*256*400 + col;
  float* ob = x1_att + (size_t)b*256*400 + col;
  float hvA = act ? hb[0] : 0.f;
  float hvB = act ? hb[400] : 0.f;
  for (int t = 0; t < 256; t++){
    float hv = hvA; hvA = hvB;
    hvB = (act && t + 2 < 256) ? hb[(size_t)(t+2)*400] : 0.f;
    float at = a_lds[t];
    float mn = fmaxf(m, at);
    float rr  = __expf(m - mn);
    float wgt = __expf(at - mn);
    den = den*rr + wgt;
    num = num*rr + wgt*hv;
    m = mn;
    if (act) ob[(size_t)t*400] = num/den;
  }
}

// ---------------- K6: out = [x1_att ; x2p] @ w_mlp^T + b, masked, f32 ----------------
__global__ void k6_out(const float* __restrict__ x1_att, const float* __restrict__ x2p,
                       const float* __restrict__ wmlp, const float* __restrict__ bmlp,
                       const int* __restrict__ seq, float* __restrict__ out){
  __shared__ float rows[8*800];
  const int tid = threadIdx.x;
  const size_t n0 = (size_t)blockIdx.x*8;
  const int b = (int)(n0 >> 8), t0 = (int)(n0 & 255);
  const int L = seq[b];
  for (int i = tid; i < 3200; i += 256){
    int r = i / 400, e = i - r*400;
    rows[r*800 + e]       = x1_att[(n0 + r)*400 + e];
    rows[r*800 + 400 + e] = x2p  [(n0 + r)*400 + e];
  }
  __syncthreads();
  for (int e = tid; e < 400; e += 256){
    float bv = bmlp[e];
    float acc[8];
    #pragma unroll
    for (int r = 0; r < 8; r++) acc[r] = bv;
    const float* wr = wmlp + (size_t)e*800;
    for (int j = 0; j < 800; j += 4){
      const f32x4 w4 = *(const f32x4*)&wr[j];
      #pragma unroll
      for (int r = 0; r < 8; r++){
        const f32x4 x4 = *(const f32x4*)&rows[r*800 + j];
        acc[r] += x4[0]*w4[0] + x4[1]*w4[1] + x4[2]*w4[2] + x4[3]*w4[3];
      }
    }
    #pragma unroll
    for (int r = 0; r < 8; r++){
      float v = (t0 + r < L) ? acc[r] : 0.f;
      out[(n0 + r)*400 + e] = v;
    }
  }
}

extern "C" void kernel_launch(void* const* d_in, const int* in_sizes, int n_in,
                              void* d_out, int out_size, void* d_ws, size_t ws_size,
                              hipStream_t stream){
  const float* x1   = (const float*)d_in[0];
  const float* x2   = (const float*)d_in[1];
  // d_in[2] = cate: unused by the reference
  const int*   seq  = (const int*)d_in[3];
  const float* wihf = (const float*)d_in[4];
  const float* whhf = (const float*)d_in[5];
  const float* bihf = (const float*)d_in[6];
  const float* bhhf = (const float*)d_in[7];
  const float* wihb = (const float*)d_in[8];
  const float* whhb = (const float*)d_in[9];
  const float* bihb = (const float*)d_in[10];
  const float* bhhb = (const float*)d_in[11];
  const float* wq   = (const float*)d_in[12];
  const float* bq   = (const float*)d_in[13];
  const float* wk   = (const float*)d_in[14];
  const float* bk   = (const float*)d_in[15];
  const float* wmha = (const float*)d_in[16];
  const float* bmha = (const float*)d_in[17];
  const float* wattn= (const float*)d_in[18];
  // d_in[19] = b_attn: cancels in softmax
  const float* wmlp = (const float*)d_in[20];
  const float* bmlp = (const float*)d_in[21];
  float* out = (float*)d_out;

  char* ws = (char*)d_ws;
  u16*  wqb    = (u16*)(ws + 0);              // 320,000 B
  u16*  wkb    = (u16*)(ws + 320000);         // 320,000
  u16*  wihfb  = (u16*)(ws + 640000);         // 640,000
  u16*  wihbb  = (u16*)(ws + 1280000);        // 640,000
  u16*  whhfb  = (u16*)(ws + 1920000);        // 320,000
  u16*  whhbb  = (u16*)(ws + 2240000);        // 320,000
  float* bgf   = (float*)(ws + 2560000);      // 3,200 (pad 4,096)
  float* bgb   = (float*)(ws + 2564096);      // 3,200 (pad 4,096)
  float* pooled= (float*)(ws + 2568192);      // 13,107,200
  float* x2p   = (float*)(ws + 15675392);     // 13,107,200
  u16*  xWf    = (u16*)(ws + 28782592);       // 13,107,200
  u16*  xWb    = (u16*)(ws + 41889792);       // 13,107,200
  float* h_ws  = (float*)(ws + 54996992);     // 13,107,200 (end ~68.1MB)
  float* x1_att= (float*)(ws + 28782592);     // overlay: xWf dead after k4

  k0_cvt  <<<dim3(1250), dim3(256), 0, stream>>>(wq, wk, wihf, wihb, whhf, whhb,
                                                 bihf, bhhf, bihb, bhhb,
                                                 wqb, wkb, wihfb, wihbb, whhfb, whhbb, bgf, bgb);
  k1_pool <<<dim3(4096), dim3(256), 0, stream>>>(x2, wqb, bq, wkb, bk, pooled);
  k3_xw   <<<dim3(256),  dim3(512), 0, stream>>>(x1, seq, wihfb, wihbb, bgf, bgb, xWf, xWb);
  k2_x2p  <<<dim3(1024), dim3(256), 0, stream>>>(pooled, wmha, bmha, x2p);
  k4_lstm <<<dim3(4),    dim3(256), 0, stream>>>(xWf, xWb, whhfb, whhbb, seq, h_ws);
  k4b_fill<<<dim3(32),   dim3(256), 0, stream>>>(seq, h_ws);
  k5_attn <<<dim3(32),   dim3(512), 0, stream>>>(h_ws, wattn, x1_att);
  k6_out  <<<dim3(1024), dim3(256), 0, stream>>>(x1_att, x2p, wmlp, bmlp, seq, out);
}

// Round 3
// 2352.023 us; speedup vs baseline: 1.6205x; 1.6205x over previous
//
// NeRTModel_60997125538302 — round 3: fix k4 register spill (2880us -> target ~200us).
// Round-2 k4 needed ~440 VGPR/wave -> compiler spilled W_hh frags to scratch, reloaded
// every step. Now: 8 waves x (6-7 gate-tile pairs) = Bf 196 VGPR; transposed MFMA
// (D rows = hu) so gates exchange is 1 ds_write_b64/pair; xW relaid [t][grp][b][hu4][gt][4]
// so activation prefetches 32B/thread coalesced at step start.
// Pipeline: k0 cvt -> k1 pool -> k3 xW -> k2 x2p -> k4 lstm -> k4b fill -> k5 attn -> k6 out.

#include <hip/hip_runtime.h>
#include <hip/hip_bf16.h>
#include <cstdint>
#include <cstddef>

typedef unsigned short u16;
typedef __attribute__((ext_vector_type(8))) short short8v;
typedef __attribute__((ext_vector_type(4))) short short4v;
typedef __attribute__((ext_vector_type(4))) float f32x4;

#define MFMA16 __builtin_amdgcn_mfma_f32_16x16x32_bf16

__device__ __forceinline__ float bf2f(u16 u){
  union { unsigned int i; float f; } v; v.i = ((unsigned int)u) << 16; return v.f;
}
__device__ __forceinline__ u16 f2bf(float f){
  union { float f; unsigned int u; } v; v.f = f;
  unsigned int r = v.u + 0x7FFFu + ((v.u >> 16) & 1u);
  return (u16)(r >> 16);
}
__device__ __forceinline__ short8v szero(){
  short8v z;
  #pragma unroll
  for (int i = 0; i < 8; i++) z[i] = 0;
  return z;
}
__device__ __forceinline__ float sigm(float x){ return 1.0f/(1.0f + __expf(-x)); }
__device__ __forceinline__ float tanh_u(float x){
  float e = __expf(2.f*x);              // overflow -> inf -> tanh -> 1 (no NaN)
  return 1.f - 2.f/(e + 1.f);
}

// ---------------- K0: convert weights f32 -> bf16 in ws; fuse LSTM biases ----------------
__global__ void k0_cvt(const float* __restrict__ wq, const float* __restrict__ wk,
                       const float* __restrict__ wihf, const float* __restrict__ wihb,
                       const float* __restrict__ whhf, const float* __restrict__ whhb,
                       const float* __restrict__ bihf, const float* __restrict__ bhhf,
                       const float* __restrict__ bihb, const float* __restrict__ bhhb,
                       u16* __restrict__ wqb, u16* __restrict__ wkb,
                       u16* __restrict__ wihfb, u16* __restrict__ wihbb,
                       u16* __restrict__ whhfb, u16* __restrict__ whhbb,
                       float* __restrict__ bgf, float* __restrict__ bgb){
  int i = blockIdx.x*256 + threadIdx.x;
  if (i < 160000){
    wqb[i] = f2bf(wq[i]); wkb[i] = f2bf(wk[i]);
    whhfb[i] = f2bf(whhf[i]); whhbb[i] = f2bf(whhb[i]);
  }
  if (i < 320000){ wihfb[i] = f2bf(wihf[i]); wihbb[i] = f2bf(wihb[i]); }
  if (i < 800){ bgf[i] = bihf[i] + bhhf[i]; bgb[i] = bihb[i] + bhhb[i]; }
}

// ---------------- K1: per-news word-attention pooling (2 news per block) ----------------
__launch_bounds__(256)
__global__ void k1_pool(const float* __restrict__ x2,
                        const u16* __restrict__ wqb, const float* __restrict__ bq,
                        const u16* __restrict__ wkb, const float* __restrict__ bk,
                        float* __restrict__ pooled){
  __shared__ u16 tok[2][6400];
  __shared__ u16 qs [2][6400];
  __shared__ u16 kss[2][6400];
  __shared__ u16 probs[2][5120];
  __shared__ float msum[2][256];
  __shared__ float tval[2][16];
  __shared__ float attw[2][16];
  const int tid = threadIdx.x;
  const size_t n0 = (size_t)blockIdx.x * 2;
  const float* src = x2 + n0*6400;
  for (int i = tid; i < 3200; i += 256){
    f32x4 v = *(const f32x4*)&src[(size_t)i*4];
    short4v s; s[0]=f2bf(v[0]); s[1]=f2bf(v[1]); s[2]=f2bf(v[2]); s[3]=f2bf(v[3]);
    int j = i / 1600, r = i - j*1600;
    ((short4v*)tok[j])[r] = s;
  }
  __syncthreads();

  const int lane = tid & 63, wv = tid >> 6;
  const int q = lane & 15, kg = lane >> 4;
  {
    const int proj = wv >> 1;                 // 0: q, 1: k
    const int ntbase = (wv & 1) ? 13 : 0;
    const int ntcnt  = (wv & 1) ? 12 : 13;    // 25 col-tiles total
    const u16* W    = proj ? wkb : wqb;
    const float* bias = proj ? bk : bq;
    short8v A[2][13];
    #pragma unroll
    for (int j = 0; j < 2; j++)
      #pragma unroll
      for (int ksi = 0; ksi < 13; ksi++){
        int e0 = ksi*32 + kg*8;
        A[j][ksi] = (e0 < 400) ? *(const short8v*)&tok[j][q*400 + e0] : szero();
      }
    u16* d0 = proj ? kss[0] : qs[0];
    u16* d1 = proj ? kss[1] : qs[1];
    for (int ti = 0; ti < ntcnt; ti++){
      int col = (ntbase + ti)*16 + q;
      float bv = bias[col];
      f32x4 acc0, acc1;
      acc0[0]=bv; acc0[1]=bv; acc0[2]=bv; acc0[3]=bv; acc1 = acc0;
      const u16* wrow = W + (size_t)col*400;
      #pragma unroll
      for (int ksi = 0; ksi < 13; ksi++){
        int e0 = ksi*32 + kg*8;
        short8v bf = (e0 < 400) ? *(const short8v*)&wrow[e0] : szero();
        acc0 = MFMA16(A[0][ksi], bf, acc0, 0, 0, 0);
        acc1 = MFMA16(A[1][ksi], bf, acc1, 0, 0, 0);
      }
      #pragma unroll
      for (int r = 0; r < 4; r++){          // D: row=(l>>4)*4+r, col=l&15
        d0[(kg*4+r)*400 + col] = f2bf(acc0[r]);
        d1[(kg*4+r)*400 + col] = f2bf(acc1[r]);
      }
    }
  }
  __syncthreads();
  // scores per (news, head, sq): dot20 over head dims, softmax over sk
  for (int r0 = tid; r0 < 640; r0 += 256){
    int j = r0 / 320, rem = r0 - j*320;
    int hh = rem >> 4, sq = rem & 15;
    const u16* qrow = &qs[j][sq*400 + hh*20];
    float qv[20];
    #pragma unroll
    for (int d5 = 0; d5 < 5; d5++){
      short4v v = *(const short4v*)&qrow[d5*4];
      qv[d5*4+0]=bf2f((u16)v[0]); qv[d5*4+1]=bf2f((u16)v[1]);
      qv[d5*4+2]=bf2f((u16)v[2]); qv[d5*4+3]=bf2f((u16)v[3]);
    }
    float sc[16]; float mx = -1e30f;
    #pragma unroll
    for (int sk = 0; sk < 16; sk++){
      const u16* krow = &kss[j][sk*400 + hh*20];
      float s = 0.f;
      #pragma unroll
      for (int d5 = 0; d5 < 5; d5++){
        short4v v = *(const short4v*)&krow[d5*4];
        s += qv[d5*4+0]*bf2f((u16)v[0]) + qv[d5*4+1]*bf2f((u16)v[1])
           + qv[d5*4+2]*bf2f((u16)v[2]) + qv[d5*4+3]*bf2f((u16)v[3]);
      }
      s *= 0.22360679775f;                   // 1/sqrt(20)
      sc[sk] = s; mx = fmaxf(mx, s);
    }
    float sum = 0.f;
    #pragma unroll
    for (int sk = 0; sk < 16; sk++){ sc[sk] = __expf(sc[sk]-mx); sum += sc[sk]; }
    float inv = 1.f/sum;
    #pragma unroll
    for (int sk = 0; sk < 16; sk++) probs[j][(hh*16+sq)*16 + sk] = f2bf(sc[sk]*inv);
  }
  __syncthreads();
  #pragma unroll
  for (int it = 0; it < 2; it++){            // mean over heads
    int idx = tid + it*256;
    int j = idx >> 8, sq = (idx >> 4) & 15, sk = idx & 15;
    float s = 0.f;
    #pragma unroll
    for (int hh = 0; hh < 20; hh++) s += bf2f(probs[j][(hh*16+sq)*16 + sk]);
    msum[j][sq*16+sk] = s * 0.05f;
  }
  __syncthreads();
  if (tid < 32){                             // mean over sk
    int j = tid >> 4, sq = tid & 15;
    float s = 0.f;
    #pragma unroll
    for (int sk = 0; sk < 16; sk++) s += msum[j][sq*16+sk];
    tval[j][sq] = s * 0.0625f;
  }
  __syncthreads();
  if (tid < 2){                              // softmax over sq (16 values)
    float mx = -1e30f;
    for (int i = 0; i < 16; i++) mx = fmaxf(mx, tval[tid][i]);
    float sum = 0.f; float ev[16];
    for (int i = 0; i < 16; i++){ ev[i] = __expf(tval[tid][i]-mx); sum += ev[i]; }
    float inv = 1.f/sum;
    for (int i = 0; i < 16; i++) attw[tid][i] = ev[i]*inv;
  }
  __syncthreads();
  for (int e = tid; e < 800; e += 256){
    int j = e / 400, c = e - j*400;
    float acc = 0.f;
    #pragma unroll
    for (int s = 0; s < 16; s++) acc += attw[j][s]*bf2f(tok[j][s*400 + c]);
    pooled[(n0+j)*400 + c] = acc;
  }
}

// ---------------- K2: x2p = pooled @ w_mlp_mha^T + b (f32 VALU) ----------------
__global__ void k2_x2p(const float* __restrict__ pooled, const float* __restrict__ wmha,
                       const float* __restrict__ bmha, float* __restrict__ x2p){
  __shared__ float rows[3200];
  const int tid = threadIdx.x;
  const size_t n0 = (size_t)blockIdx.x*8;
  for (int i = tid; i < 3200; i += 256) rows[i] = pooled[n0*400 + i];
  __syncthreads();
  for (int j = tid; j < 400; j += 256){
    float bv = bmha[j];
    float acc[8];
    #pragma unroll
    for (int r = 0; r < 8; r++) acc[r] = bv;
    const float* wr = wmha + (size_t)j*400;
    for (int e = 0; e < 400; e += 4){
      const f32x4 w4 = *(const f32x4*)&wr[e];
      #pragma unroll
      for (int r = 0; r < 8; r++){
        const f32x4 x4 = *(const f32x4*)&rows[r*400 + e];
        acc[r] += x4[0]*w4[0] + x4[1]*w4[1] + x4[2]*w4[2] + x4[3]*w4[3];
      }
    }
    #pragma unroll
    for (int r = 0; r < 8; r++) x2p[(n0+r)*400 + j] = acc[r];
  }
}

// ---------------- K3: xW = x @ W_ih^T + (b_ih+b_hh), layout [t][grp][b16][hu4][gt][4] bf16 ----------------
__launch_bounds__(512)
__global__ void k3_xw(const float* __restrict__ x1, const int* __restrict__ seq,
                      const u16* __restrict__ wihfb, const u16* __restrict__ wihbb,
                      const float* __restrict__ bgf, const float* __restrict__ bgb,
                      u16* __restrict__ xWf, u16* __restrict__ xWb){
  __shared__ u16 xf[12800];
  __shared__ u16 xb[12800];
  const int tid = threadIdx.x;
  const int t = blockIdx.x;
  for (int i = tid; i < 3200; i += 512){
    int b = i / 100, e4 = i - b*100;
    f32x4 vf = *(const f32x4*)&x1[((size_t)b*256 + t)*400 + e4*4];
    int rb = seq[b] - 1 - t; if (rb < 0) rb = 0;     // clip(L-1-t, 0, T-1)
    f32x4 vb = *(const f32x4*)&x1[((size_t)b*256 + rb)*400 + e4*4];
    short4v sf, sb;
    #pragma unroll
    for (int r = 0; r < 4; r++){ sf[r] = f2bf(vf[r]); sb[r] = f2bf(vb[r]); }
    ((short4v*)xf)[i] = sf;
    ((short4v*)xb)[i] = sb;
  }
  __syncthreads();
  const int lane = tid & 63, wv = tid >> 6;
  const int dir = wv >> 2, wl = wv & 3;
  const u16* xs = dir ? xb : xf;
  const u16* W  = dir ? wihbb : wihfb;
  const float* bg = dir ? bgb : bgf;
  u16* xW = dir ? xWb : xWf;
  const int q = lane & 15, kg = lane >> 4;
  short8v A[2][13];
  #pragma unroll
  for (int mt = 0; mt < 2; mt++)
    #pragma unroll
    for (int ksi = 0; ksi < 13; ksi++){
      int e0 = ksi*32 + kg*8;
      A[mt][ksi] = (e0 < 400) ? *(const short8v*)&xs[(mt*16 + q)*400 + e0] : szero();
    }
  for (int nt = wl; nt < 50; nt += 4){
    int g = nt*16 + q;                       // gate row 0..799 (i,f,g,o blocks of 200)
    float bv = bg[g];
    f32x4 acc0, acc1;
    acc0[0]=bv; acc0[1]=bv; acc0[2]=bv; acc0[3]=bv; acc1 = acc0;
    const u16* wrow = W + (size_t)g*400;
    #pragma unroll
    for (int ksi = 0; ksi < 13; ksi++){
      int e0 = ksi*32 + kg*8;
      short8v bf = (e0 < 400) ? *(const short8v*)&wrow[e0] : szero();
      acc0 = MFMA16(A[0][ksi], bf, acc0, 0,0,0);
      acc1 = MFMA16(A[1][ksi], bf, acc1, 0,0,0);
    }
    int gt = g / 200, hu = g - gt*200;
    int hu4 = hu >> 2, rr = hu & 3;
    #pragma unroll
    for (int r = 0; r < 4; r++){
      int bl = kg*4 + r;                     // D rows = batch rows (mt*16 + bl)
      xW[((((size_t)t*2 + 0)*16 + bl)*50 + hu4)*16 + gt*4 + rr] = f2bf(acc0[r]);
      xW[((((size_t)t*2 + 1)*16 + bl)*50 + hu4)*16 + gt*4 + rr] = f2bf(acc1[r]);
    }
  }
}

// ---------------- K4: sequential BiLSTM. grid 4 = (dir, batch group of 16), 512 thr. ----------------
// 8 waves x 6-7 (gate,tile) pairs; W_hh resident (196 VGPR); transposed MFMA D[hu][b];
// gates exchange via [gt][b][hu] LDS, b64 writes/reads; xW prefetched 32B/thread.
__launch_bounds__(512, 2)
__global__ void k4_lstm(const u16* __restrict__ xWf, const u16* __restrict__ xWb,
                        const u16* __restrict__ whhfb, const u16* __restrict__ whhbb,
                        const int* __restrict__ seq, float* __restrict__ h_ws){
  __shared__ __align__(16) u16 h_lds[3200];      // h_{t-1} bf16 [b16][hu200]
  __shared__ __align__(16) u16 gates[12800];     // [gt][b16][hu200] bf16
  __shared__ int Ls[16];
  const int tid = threadIdx.x;
  const int dir = blockIdx.x >> 1, grp = blockIdx.x & 1;
  const u16* xWd = dir ? xWb : xWf;
  const u16* whh = dir ? whhbb : whhfb;
  if (tid < 16) Ls[tid] = seq[grp*16 + tid];
  for (int i = tid; i < 3200; i += 512) h_lds[i] = 0;
  const int lane = tid & 63, wv = tid >> 6;
  const int q = lane & 15, kg = lane >> 4;
  const int npair = (wv < 4) ? 7 : 6;            // pairs p = wv + 8j, p<52
  short8v Bf[7][7];                              // W_hh A-fragments: lane q = row hu_local
  #pragma unroll
  for (int j = 0; j < 7; j++){
    int p = wv + 8*j;
    bool pv = p < 52;
    int gt = pv ? p/13 : 0, nt = pv ? p - (p/13)*13 : 0;
    int hl = nt*16 + q;
    #pragma unroll
    for (int ksi = 0; ksi < 7; ksi++){
      int k0 = ksi*32 + kg*8;
      Bf[j][ksi] = (pv && hl < 200 && k0 < 200)
        ? *(const short8v*)&whh[(size_t)(gt*200 + hl)*200 + k0] : szero();
    }
  }
  float cst[8];
  #pragma unroll
  for (int i = 0; i < 8; i++) cst[i] = 0.f;
  const int bl0 = tid / 50,  hu40 = tid - bl0*50;          // quad 0 (always valid)
  const int qd1 = tid + 512;
  const int bl1 = qd1 / 50,  hu41 = qd1 - bl1*50;          // quad 1 (tid<288)
  __syncthreads();
  #pragma unroll 1
  for (int t = 0; t < 256; t++){
    // prefetch this step's xW (latency hides under MFMA phase)
    const u16* xwt = xWd + ((size_t)t*2 + grp)*12800;
    short8v xw0a = *(const short8v*)&xwt[tid*16];
    short8v xw0b = *(const short8v*)&xwt[tid*16 + 8];
    short8v xw1a = szero(), xw1b = szero();
    if (tid < 288){
      xw1a = *(const short8v*)&xwt[qd1*16];
      xw1b = *(const short8v*)&xwt[qd1*16 + 8];
    }
    // MFMA: D[hu_local][b] = W_tile @ h^T; 7 independent acc chains
    f32x4 acc[7];
    #pragma unroll
    for (int j = 0; j < 7; j++){ acc[j][0]=0.f; acc[j][1]=0.f; acc[j][2]=0.f; acc[j][3]=0.f; }
    #pragma unroll
    for (int ksi = 0; ksi < 7; ksi++){
      int k0 = ksi*32 + kg*8;
      short8v bh = (k0 < 200) ? *(const short8v*)&h_lds[q*200 + k0] : szero();
      #pragma unroll
      for (int j = 0; j < 7; j++)
        if (j < npair) acc[j] = MFMA16(Bf[j][ksi], bh, acc[j], 0,0,0);
    }
    #pragma unroll
    for (int j = 0; j < 7; j++){
      if (j < npair){
        int p = wv + 8*j;
        int gt = p/13, nt = p - (p/13)*13;
        int hu0 = nt*16 + kg*4;
        if (hu0 < 200){
          short4v g4;
          #pragma unroll
          for (int r = 0; r < 4; r++) g4[r] = (short)f2bf(acc[j][r]);
          *(short4v*)&gates[(gt*16 + q)*200 + hu0] = g4;   // q = b (D col)
        }
      }
    }
    __syncthreads();                                   // gates + xw ready
    // activation: quad = 4 consecutive hu of one b; all 4 gates in-lane
    {
      int base = bl0*200 + hu40*4;
      short4v gi4 = *(const short4v*)&gates[base];
      short4v gf4 = *(const short4v*)&gates[3200 + base];
      short4v gg4 = *(const short4v*)&gates[6400 + base];
      short4v go4 = *(const short4v*)&gates[9600 + base];
      short4v hp; f32x4 hw;
      #pragma unroll
      for (int r = 0; r < 4; r++){
        float gi = bf2f((u16)gi4[r]) + bf2f((u16)xw0a[r]);
        float gf = bf2f((u16)gf4[r]) + bf2f((u16)xw0a[4+r]);
        float gg = bf2f((u16)gg4[r]) + bf2f((u16)xw0b[r]);
        float go = bf2f((u16)go4[r]) + bf2f((u16)xw0b[4+r]);
        float c = sigm(gf)*cst[r] + sigm(gi)*tanh_u(gg);
        cst[r] = c;
        float hv = sigm(go)*tanh_u(c);
        hp[r] = (short)f2bf(hv); hw[r] = hv;
      }
      *(short4v*)&h_lds[base] = hp;
      int gb = grp*16 + bl0;
      if (dir == 0){
        *(f32x4*)&h_ws[((size_t)gb*256 + t)*400 + hu40*4] = hw;
      } else {
        int tp = Ls[bl0] - 1 - t;
        if (tp >= 0) *(f32x4*)&h_ws[((size_t)gb*256 + tp)*400 + 200 + hu40*4] = hw;
      }
    }
    if (tid < 288){
      int base = bl1*200 + hu41*4;
      short4v gi4 = *(const short4v*)&gates[base];
      short4v gf4 = *(const short4v*)&gates[3200 + base];
      short4v gg4 = *(const short4v*)&gates[6400 + base];
      short4v go4 = *(const short4v*)&gates[9600 + base];
      short4v hp; f32x4 hw;
      #pragma unroll
      for (int r = 0; r < 4; r++){
        float gi = bf2f((u16)gi4[r]) + bf2f((u16)xw1a[r]);
        float gf = bf2f((u16)gf4[r]) + bf2f((u16)xw1a[4+r]);
        float gg = bf2f((u16)gg4[r]) + bf2f((u16)xw1b[r]);
        float go = bf2f((u16)go4[r]) + bf2f((u16)xw1b[4+r]);
        float c = sigm(gf)*cst[4+r] + sigm(gi)*tanh_u(gg);
        cst[4+r] = c;
        float hv = sigm(go)*tanh_u(c);
        hp[r] = (short)f2bf(hv); hw[r] = hv;
      }
      *(short4v*)&h_lds[base] = hp;
      int gb = grp*16 + bl1;
      if (dir == 0){
        *(f32x4*)&h_ws[((size_t)gb*256 + t)*400 + hu41*4] = hw;
      } else {
        int tp = Ls[bl1] - 1 - t;
        if (tp >= 0) *(f32x4*)&h_ws[((size_t)gb*256 + tp)*400 + 200 + hu41*4] = hw;
      }
    }
    __syncthreads();                                   // h_lds ready for t+1
  }
}

// ---------------- K4b: fill bwd rows t>=L with h_bwd_r[0] (== stored row L-1) ----------------
__global__ void k4b_fill(const int* __restrict__ seq, float* __restrict__ h_ws){
  const int b = blockIdx.x;
  const int L = seq[b];
  const int cnt = (256 - L)*200;
  const float* src = h_ws + ((size_t)b*256 + (L-1))*400 + 200;
  for (int i = threadIdx.x; i < cnt; i += 256){
    int tt = L + i/200, cc = i - (i/200)*200;
    h_ws[((size_t)b*256 + tt)*400 + 200 + cc] = src[cc];
  }
}

// ---------------- K5: causal growing-window attention (query term cancels) ----------------
__launch_bounds__(512)
__global__ void k5_attn(const float* __restrict__ h_ws, const float* __restrict__ wattn,
                        float* __restrict__ x1_att){
  __shared__ float a_lds[256];
  const int tid = threadIdx.x;
  const int b = blockIdx.x;
  const int lane = tid & 63, wv = tid >> 6;
  for (int row = wv*32; row < wv*32 + 32; row++){
    float s = 0.f;
    for (int j = lane; j < 400; j += 64)
      s += h_ws[((size_t)b*256 + row)*400 + j] * wattn[j];
    #pragma unroll
    for (int m = 32; m > 0; m >>= 1) s += __shfl_xor(s, m, 64);
    if (lane == 0) a_lds[row] = s;
  }
  __syncthreads();
  const int col = tid;
  const bool act = col < 400;
  float m = -1e30f, den = 0.f, num = 0.f;
  const float* hb = h_ws + (size_t)b*256*400 + col;
  float* ob = x1_att + (size_t)b*256*400 + col;
  float hvA = act ? hb[0] : 0.f;
  float hvB = act ? hb[400] : 0.f;
  for (int t = 0; t < 256; t++){
    float hv = hvA; hvA = hvB;
    hvB = (act && t + 2 < 256) ? hb[(size_t)(t+2)*400] : 0.f;
    float at = a_lds[t];
    float mn = fmaxf(m, at);
    float rr  = __expf(m - mn);
    float wgt = __expf(at - mn);
    den = den*rr + wgt;
    num = num*rr + wgt*hv;
    m = mn;
    if (act) ob[(size_t)t*400] = num/den;
  }
}

// ---------------- K6: out = [x1_att ; x2p] @ w_mlp^T + b, masked, f32 ----------------
__global__ void k6_out(const float* __restrict__ x1_att, const float* __restrict__ x2p,
                       const float* __restrict__ wmlp, const float* __restrict__ bmlp,
                       const int* __restrict__ seq, float* __restrict__ out){
  __shared__ float rows[8*800];
  const int tid = threadIdx.x;
  const size_t n0 = (size_t)blockIdx.x*8;
  const int b = (int)(n0 >> 8), t0 = (int)(n0 & 255);
  const int L = seq[b];
  for (int i = tid; i < 3200; i += 256){
    int r = i / 400, e = i - r*400;
    rows[r*800 + e]       = x1_att[(n0 + r)*400 + e];
    rows[r*800 + 400 + e] = x2p  [(n0 + r)*400 + e];
  }
  __syncthreads();
  for (int e = tid; e < 400; e += 256){
    float bv = bmlp[e];
    float acc[8];
    #pragma unroll
    for (int r = 0; r < 8; r++) acc[r] = bv;
    const float* wr = wmlp + (size_t)e*800;
    for (int j = 0; j < 800; j += 4){
      const f32x4 w4 = *(const f32x4*)&wr[j];
      #pragma unroll
      for (int r = 0; r < 8; r++){
        const f32x4 x4 = *(const f32x4*)&rows[r*800 + j];
        acc[r] += x4[0]*w4[0] + x4[1]*w4[1] + x4[2]*w4[2] + x4[3]*w4[3];
      }
    }
    #pragma unroll
    for (int r = 0; r < 8; r++){
      float v = (t0 + r < L) ? acc[r] : 0.f;
      out[(n0 + r)*400 + e] = v;
    }
  }
}

extern "C" void kernel_launch(void* const* d_in, const int* in_sizes, int n_in,
                              void* d_out, int out_size, void* d_ws, size_t ws_size,
                              hipStream_t stream){
  const float* x1   = (const float*)d_in[0];
  const float* x2   = (const float*)d_in[1];
  // d_in[2] = cate: unused by the reference
  const int*   seq  = (const int*)d_in[3];
  const float* wihf = (const float*)d_in[4];
  const float* whhf = (const float*)d_in[5];
  const float* bihf = (const float*)d_in[6];
  const float* bhhf = (const float*)d_in[7];
  const float* wihb = (const float*)d_in[8];
  const float* whhb = (const float*)d_in[9];
  const float* bihb = (const float*)d_in[10];
  const float* bhhb = (const float*)d_in[11];
  const float* wq   = (const float*)d_in[12];
  const float* bq   = (const float*)d_in[13];
  const float* wk   = (const float*)d_in[14];
  const float* bk   = (const float*)d_in[15];
  const float* wmha = (const float*)d_in[16];
  const float* bmha = (const float*)d_in[17];
  const float* wattn= (const float*)d_in[18];
  // d_in[19] = b_attn: cancels in softmax
  const float* wmlp = (const float*)d_in[20];
  const float* bmlp = (const float*)d_in[21];
  float* out = (float*)d_out;

  char* ws = (char*)d_ws;
  u16*  wqb    = (u16*)(ws + 0);              // 320,000 B
  u16*  wkb    = (u16*)(ws + 320000);         // 320,000
  u16*  wihfb  = (u16*)(ws + 640000);         // 640,000
  u16*  wihbb  = (u16*)(ws + 1280000);        // 640,000
  u16*  whhfb  = (u16*)(ws + 1920000);        // 320,000
  u16*  whhbb  = (u16*)(ws + 2240000);        // 320,000
  float* bgf   = (float*)(ws + 2560000);      // 3,200 (pad 4,096)
  float* bgb   = (float*)(ws + 2564096);      // 3,200 (pad 4,096)
  float* pooled= (float*)(ws + 2568192);      // 13,107,200
  float* x2p   = (float*)(ws + 15675392);     // 13,107,200
  u16*  xWf    = (u16*)(ws + 28782592);       // 13,107,200
  u16*  xWb    = (u16*)(ws + 41889792);       // 13,107,200
  float* h_ws  = (float*)(ws + 54996992);     // 13,107,200 (end ~68.1MB)
  float* x1_att= (float*)(ws + 28782592);     // overlay: xWf dead after k4

  k0_cvt  <<<dim3(1250), dim3(256), 0, stream>>>(wq, wk, wihf, wihb, whhf, whhb,
                                                 bihf, bhhf, bihb, bhhb,
                                                 wqb, wkb, wihfb, wihbb, whhfb, whhbb, bgf, bgb);
  k1_pool <<<dim3(4096), dim3(256), 0, stream>>>(x2, wqb, bq, wkb, bk, pooled);
  k3_xw   <<<dim3(256),  dim3(512), 0, stream>>>(x1, seq, wihfb, wihbb, bgf, bgb, xWf, xWb);
  k2_x2p  <<<dim3(1024), dim3(256), 0, stream>>>(pooled, wmha, bmha, x2p);
  k4_lstm <<<dim3(4),    dim3(512), 0, stream>>>(xWf, xWb, whhfb, whhbb, seq, h_ws);
  k4b_fill<<<dim3(32),   dim3(256), 0, stream>>>(seq, h_ws);
  k5_attn <<<dim3(32),   dim3(512), 0, stream>>>(h_ws, wattn, x1_att);
  k6_out  <<<dim3(1024), dim3(256), 0, stream>>>(x1_att, x2p, wmlp, bmlp, seq, out);
}

// Round 4
// 1997.605 us; speedup vs baseline: 1.9080x; 1.1774x over previous
//
// NeRTModel_60997125538302 — round 4: actually de-spill k4.
// Round-3 launch_bounds(512,2) is only a FLOOR on waves/EU -> allocator chose 4 waves/SIMD
// -> 128-VGPR cap -> ~140 regs spilled, W_hh re-streamed from L2 each step (1400us).
// Fix: amdgpu_waves_per_eu(2,2) pins 2 waves/SIMD (256-VGPR cap) AND the working set is
// trimmed to ~248: 6 reg-resident W_hh pairs/wave (168 VGPR) + 4 leftover pairs in a
// lane-ordered LDS fragment pool (conflict-free ds_read_b128), h-frags preloaded once/step,
// 2 live accumulators. Everything else identical to round 3.

#include <hip/hip_runtime.h>
#include <hip/hip_bf16.h>
#include <cstdint>
#include <cstddef>

typedef unsigned short u16;
typedef __attribute__((ext_vector_type(8))) short short8v;
typedef __attribute__((ext_vector_type(4))) short short4v;
typedef __attribute__((ext_vector_type(4))) float f32x4;

#define MFMA16 __builtin_amdgcn_mfma_f32_16x16x32_bf16

__device__ __forceinline__ float bf2f(u16 u){
  union { unsigned int i; float f; } v; v.i = ((unsigned int)u) << 16; return v.f;
}
__device__ __forceinline__ u16 f2bf(float f){
  union { float f; unsigned int u; } v; v.f = f;
  unsigned int r = v.u + 0x7FFFu + ((v.u >> 16) & 1u);
  return (u16)(r >> 16);
}
__device__ __forceinline__ short8v szero(){
  short8v z;
  #pragma unroll
  for (int i = 0; i < 8; i++) z[i] = 0;
  return z;
}
__device__ __forceinline__ float sigm(float x){ return 1.0f/(1.0f + __expf(-x)); }
__device__ __forceinline__ float tanh_u(float x){
  float e = __expf(2.f*x);              // overflow -> inf -> tanh -> 1 (no NaN)
  return 1.f - 2.f/(e + 1.f);
}

// ---------------- K0: convert weights f32 -> bf16 in ws; fuse LSTM biases ----------------
__global__ void k0_cvt(const float* __restrict__ wq, const float* __restrict__ wk,
                       const float* __restrict__ wihf, const float* __restrict__ wihb,
                       const float* __restrict__ whhf, const float* __restrict__ whhb,
                       const float* __restrict__ bihf, const float* __restrict__ bhhf,
                       const float* __restrict__ bihb, const float* __restrict__ bhhb,
                       u16* __restrict__ wqb, u16* __restrict__ wkb,
                       u16* __restrict__ wihfb, u16* __restrict__ wihbb,
                       u16* __restrict__ whhfb, u16* __restrict__ whhbb,
                       float* __restrict__ bgf, float* __restrict__ bgb){
  int i = blockIdx.x*256 + threadIdx.x;
  if (i < 160000){
    wqb[i] = f2bf(wq[i]); wkb[i] = f2bf(wk[i]);
    whhfb[i] = f2bf(whhf[i]); whhbb[i] = f2bf(whhb[i]);
  }
  if (i < 320000){ wihfb[i] = f2bf(wihf[i]); wihbb[i] = f2bf(wihb[i]); }
  if (i < 800){ bgf[i] = bihf[i] + bhhf[i]; bgb[i] = bihb[i] + bhhb[i]; }
}

// ---------------- K1: per-news word-attention pooling (2 news per block) ----------------
__launch_bounds__(256)
__global__ void k1_pool(const float* __restrict__ x2,
                        const u16* __restrict__ wqb, const float* __restrict__ bq,
                        const u16* __restrict__ wkb, const float* __restrict__ bk,
                        float* __restrict__ pooled){
  __shared__ u16 tok[2][6400];
  __shared__ u16 qs [2][6400];
  __shared__ u16 kss[2][6400];
  __shared__ u16 probs[2][5120];
  __shared__ float msum[2][256];
  __shared__ float tval[2][16];
  __shared__ float attw[2][16];
  const int tid = threadIdx.x;
  const size_t n0 = (size_t)blockIdx.x * 2;
  const float* src = x2 + n0*6400;
  for (int i = tid; i < 3200; i += 256){
    f32x4 v = *(const f32x4*)&src[(size_t)i*4];
    short4v s; s[0]=f2bf(v[0]); s[1]=f2bf(v[1]); s[2]=f2bf(v[2]); s[3]=f2bf(v[3]);
    int j = i / 1600, r = i - j*1600;
    ((short4v*)tok[j])[r] = s;
  }
  __syncthreads();

  const int lane = tid & 63, wv = tid >> 6;
  const int q = lane & 15, kg = lane >> 4;
  {
    const int proj = wv >> 1;                 // 0: q, 1: k
    const int ntbase = (wv & 1) ? 13 : 0;
    const int ntcnt  = (wv & 1) ? 12 : 13;    // 25 col-tiles total
    const u16* W    = proj ? wkb : wqb;
    const float* bias = proj ? bk : bq;
    short8v A[2][13];
    #pragma unroll
    for (int j = 0; j < 2; j++)
      #pragma unroll
      for (int ksi = 0; ksi < 13; ksi++){
        int e0 = ksi*32 + kg*8;
        A[j][ksi] = (e0 < 400) ? *(const short8v*)&tok[j][q*400 + e0] : szero();
      }
    u16* d0 = proj ? kss[0] : qs[0];
    u16* d1 = proj ? kss[1] : qs[1];
    for (int ti = 0; ti < ntcnt; ti++){
      int col = (ntbase + ti)*16 + q;
      float bv = bias[col];
      f32x4 acc0, acc1;
      acc0[0]=bv; acc0[1]=bv; acc0[2]=bv; acc0[3]=bv; acc1 = acc0;
      const u16* wrow = W + (size_t)col*400;
      #pragma unroll
      for (int ksi = 0; ksi < 13; ksi++){
        int e0 = ksi*32 + kg*8;
        short8v bf = (e0 < 400) ? *(const short8v*)&wrow[e0] : szero();
        acc0 = MFMA16(A[0][ksi], bf, acc0, 0, 0, 0);
        acc1 = MFMA16(A[1][ksi], bf, acc1, 0, 0, 0);
      }
      #pragma unroll
      for (int r = 0; r < 4; r++){          // D: row=(l>>4)*4+r, col=l&15
        d0[(kg*4+r)*400 + col] = f2bf(acc0[r]);
        d1[(kg*4+r)*400 + col] = f2bf(acc1[r]);
      }
    }
  }
  __syncthreads();
  // scores per (news, head, sq): dot20 over head dims, softmax over sk
  for (int r0 = tid; r0 < 640; r0 += 256){
    int j = r0 / 320, rem = r0 - j*320;
    int hh = rem >> 4, sq = rem & 15;
    const u16* qrow = &qs[j][sq*400 + hh*20];
    float qv[20];
    #pragma unroll
    for (int d5 = 0; d5 < 5; d5++){
      short4v v = *(const short4v*)&qrow[d5*4];
      qv[d5*4+0]=bf2f((u16)v[0]); qv[d5*4+1]=bf2f((u16)v[1]);
      qv[d5*4+2]=bf2f((u16)v[2]); qv[d5*4+3]=bf2f((u16)v[3]);
    }
    float sc[16]; float mx = -1e30f;
    #pragma unroll
    for (int sk = 0; sk < 16; sk++){
      const u16* krow = &kss[j][sk*400 + hh*20];
      float s = 0.f;
      #pragma unroll
      for (int d5 = 0; d5 < 5; d5++){
        short4v v = *(const short4v*)&krow[d5*4];
        s += qv[d5*4+0]*bf2f((u16)v[0]) + qv[d5*4+1]*bf2f((u16)v[1])
           + qv[d5*4+2]*bf2f((u16)v[2]) + qv[d5*4+3]*bf2f((u16)v[3]);
      }
      s *= 0.22360679775f;                   // 1/sqrt(20)
      sc[sk] = s; mx = fmaxf(mx, s);
    }
    float sum = 0.f;
    #pragma unroll
    for (int sk = 0; sk < 16; sk++){ sc[sk] = __expf(sc[sk]-mx); sum += sc[sk]; }
    float inv = 1.f/sum;
    #pragma unroll
    for (int sk = 0; sk < 16; sk++) probs[j][(hh*16+sq)*16 + sk] = f2bf(sc[sk]*inv);
  }
  __syncthreads();
  #pragma unroll
  for (int it = 0; it < 2; it++){            // mean over heads
    int idx = tid + it*256;
    int j = idx >> 8, sq = (idx >> 4) & 15, sk = idx & 15;
    float s = 0.f;
    #pragma unroll
    for (int hh = 0; hh < 20; hh++) s += bf2f(probs[j][(hh*16+sq)*16 + sk]);
    msum[j][sq*16+sk] = s * 0.05f;
  }
  __syncthreads();
  if (tid < 32){                             // mean over sk
    int j = tid >> 4, sq = tid & 15;
    float s = 0.f;
    #pragma unroll
    for (int sk = 0; sk < 16; sk++) s += msum[j][sq*16+sk];
    tval[j][sq] = s * 0.0625f;
  }
  __syncthreads();
  if (tid < 2){                              // softmax over sq (16 values)
    float mx = -1e30f;
    for (int i = 0; i < 16; i++) mx = fmaxf(mx, tval[tid][i]);
    float sum = 0.f; float ev[16];
    for (int i = 0; i < 16; i++){ ev[i] = __expf(tval[tid][i]-mx); sum += ev[i]; }
    float inv = 1.f/sum;
    for (int i = 0; i < 16; i++) attw[tid][i] = ev[i]*inv;
  }
  __syncthreads();
  for (int e = tid; e < 800; e += 256){
    int j = e / 400, c = e - j*400;
    float acc = 0.f;
    #pragma unroll
    for (int s = 0; s < 16; s++) acc += attw[j][s]*bf2f(tok[j][s*400 + c]);
    pooled[(n0+j)*400 + c] = acc;
  }
}

// ---------------- K2: x2p = pooled @ w_mlp_mha^T + b (f32 VALU) ----------------
__global__ void k2_x2p(const float* __restrict__ pooled, const float* __restrict__ wmha,
                       const float* __restrict__ bmha, float* __restrict__ x2p){
  __shared__ float rows[3200];
  const int tid = threadIdx.x;
  const size_t n0 = (size_t)blockIdx.x*8;
  for (int i = tid; i < 3200; i += 256) rows[i] = pooled[n0*400 + i];
  __syncthreads();
  for (int j = tid; j < 400; j += 256){
    float bv = bmha[j];
    float acc[8];
    #pragma unroll
    for (int r = 0; r < 8; r++) acc[r] = bv;
    const float* wr = wmha + (size_t)j*400;
    for (int e = 0; e < 400; e += 4){
      const f32x4 w4 = *(const f32x4*)&wr[e];
      #pragma unroll
      for (int r = 0; r < 8; r++){
        const f32x4 x4 = *(const f32x4*)&rows[r*400 + e];
        acc[r] += x4[0]*w4[0] + x4[1]*w4[1] + x4[2]*w4[2] + x4[3]*w4[3];
      }
    }
    #pragma unroll
    for (int r = 0; r < 8; r++) x2p[(n0+r)*400 + j] = acc[r];
  }
}

// ---------------- K3: xW = x @ W_ih^T + (b_ih+b_hh), layout [t][grp][b16][hu4][gt][4] bf16 ----------------
__launch_bounds__(512)
__global__ void k3_xw(const float* __restrict__ x1, const int* __restrict__ seq,
                      const u16* __restrict__ wihfb, const u16* __restrict__ wihbb,
                      const float* __restrict__ bgf, const float* __restrict__ bgb,
                      u16* __restrict__ xWf, u16* __restrict__ xWb){
  __shared__ u16 xf[12800];
  __shared__ u16 xb[12800];
  const int tid = threadIdx.x;
  const int t = blockIdx.x;
  for (int i = tid; i < 3200; i += 512){
    int b = i / 100, e4 = i - b*100;
    f32x4 vf = *(const f32x4*)&x1[((size_t)b*256 + t)*400 + e4*4];
    int rb = seq[b] - 1 - t; if (rb < 0) rb = 0;     // clip(L-1-t, 0, T-1)
    f32x4 vb = *(const f32x4*)&x1[((size_t)b*256 + rb)*400 + e4*4];
    short4v sf, sb;
    #pragma unroll
    for (int r = 0; r < 4; r++){ sf[r] = f2bf(vf[r]); sb[r] = f2bf(vb[r]); }
    ((short4v*)xf)[i] = sf;
    ((short4v*)xb)[i] = sb;
  }
  __syncthreads();
  const int lane = tid & 63, wv = tid >> 6;
  const int dir = wv >> 2, wl = wv & 3;
  const u16* xs = dir ? xb : xf;
  const u16* W  = dir ? wihbb : wihfb;
  const float* bg = dir ? bgb : bgf;
  u16* xW = dir ? xWb : xWf;
  const int q = lane & 15, kg = lane >> 4;
  short8v A[2][13];
  #pragma unroll
  for (int mt = 0; mt < 2; mt++)
    #pragma unroll
    for (int ksi = 0; ksi < 13; ksi++){
      int e0 = ksi*32 + kg*8;
      A[mt][ksi] = (e0 < 400) ? *(const short8v*)&xs[(mt*16 + q)*400 + e0] : szero();
    }
  for (int nt = wl; nt < 50; nt += 4){
    int g = nt*16 + q;                       // gate row 0..799 (i,f,g,o blocks of 200)
    float bv = bg[g];
    f32x4 acc0, acc1;
    acc0[0]=bv; acc0[1]=bv; acc0[2]=bv; acc0[3]=bv; acc1 = acc0;
    const u16* wrow = W + (size_t)g*400;
    #pragma unroll
    for (int ksi = 0; ksi < 13; ksi++){
      int e0 = ksi*32 + kg*8;
      short8v bf = (e0 < 400) ? *(const short8v*)&wrow[e0] : szero();
      acc0 = MFMA16(A[0][ksi], bf, acc0, 0,0,0);
      acc1 = MFMA16(A[1][ksi], bf, acc1, 0,0,0);
    }
    int gt = g / 200, hu = g - gt*200;
    int hu4 = hu >> 2, rr = hu & 3;
    #pragma unroll
    for (int r = 0; r < 4; r++){
      int bl = kg*4 + r;                     // D rows = batch rows (mt*16 + bl)
      xW[((((size_t)t*2 + 0)*16 + bl)*50 + hu4)*16 + gt*4 + rr] = f2bf(acc0[r]);
      xW[((((size_t)t*2 + 1)*16 + bl)*50 + hu4)*16 + gt*4 + rr] = f2bf(acc1[r]);
    }
  }
}

// ---------------- K4: sequential BiLSTM. grid 4 = (dir, batch group of 16), 512 thr. ----------------
// waves_per_eu(2,2) pins 256-VGPR cap; 6 reg pairs/wave (168 VGPR) + 4 pairs in LDS pool;
// h-frags preloaded once/step; 2 live accs; gates via [gt][b][hu] LDS b64.
__attribute__((amdgpu_waves_per_eu(2, 2)))
__global__ void __launch_bounds__(512) k4_lstm(
                        const u16* __restrict__ xWf, const u16* __restrict__ xWb,
                        const u16* __restrict__ whhfb, const u16* __restrict__ whhbb,
                        const int* __restrict__ seq, float* __restrict__ h_ws){
  __shared__ __align__(16) u16 h_lds[3200];      // h_{t-1} bf16 [b16][hu200]
  __shared__ __align__(16) u16 gates[12800];     // [gt][b16][hu200] bf16
  __shared__ __align__(16) u16 wpool[4*7*64*8];  // pairs 48..51, fragment-ordered (28.7KB)
  __shared__ int Ls[16];
  const int tid = threadIdx.x;
  const int dir = blockIdx.x >> 1, grp = blockIdx.x & 1;
  const u16* xWd = dir ? xWb : xWf;
  const u16* whh = dir ? whhbb : whhfb;
  if (tid < 16) Ls[tid] = seq[grp*16 + tid];
  for (int i = tid; i < 3200; i += 512) h_lds[i] = 0;
  const int lane = tid & 63, wv = tid >> 6;
  const int q = lane & 15, kg = lane >> 4;
  // fill LDS fragment pool: pairs p=48..51 -> (gt=3, nt=9+pl)
  for (int idx = tid; idx < 4*7*64; idx += 512){
    int pl = idx / 448, rem = idx - pl*448;
    int ksi = rem >> 6, l = rem & 63;
    int qq = l & 15, kk = l >> 4;
    int hl = (9 + pl)*16 + qq;
    int k0 = ksi*32 + kk*8;
    short8v f = (hl < 200 && k0 < 200)
      ? *(const short8v*)&whh[(size_t)(3*200 + hl)*200 + k0] : szero();
    ((short8v*)wpool)[idx] = f;
  }
  // register-resident pairs: p = wv + 8*j, j=0..5 (all p < 48)
  short8v Bf[6][7];
  #pragma unroll
  for (int j = 0; j < 6; j++){
    int p = wv + 8*j;
    int gt = p/13, nt = p - gt*13;
    int hl = nt*16 + q;
    #pragma unroll
    for (int ksi = 0; ksi < 7; ksi++){
      int k0 = ksi*32 + kg*8;
      Bf[j][ksi] = (hl < 200 && k0 < 200)
        ? *(const short8v*)&whh[(size_t)(gt*200 + hl)*200 + k0] : szero();
    }
  }
  float cst[8];
  #pragma unroll
  for (int i = 0; i < 8; i++) cst[i] = 0.f;
  const int bl0 = tid / 50,  hu40 = tid - bl0*50;          // quad 0 (always valid)
  const int qd1 = tid + 512;
  const int bl1 = qd1 / 50,  hu41 = qd1 - bl1*50;          // quad 1 (tid<288)
  __syncthreads();
  #pragma unroll 1
  for (int t = 0; t < 256; t++){
    // prefetch this step's xW (latency hides under MFMA phase)
    const u16* xwt = xWd + ((size_t)t*2 + grp)*12800;
    short8v xw0a = *(const short8v*)&xwt[tid*16];
    short8v xw0b = *(const short8v*)&xwt[tid*16 + 8];
    short8v xw1a = szero(), xw1b = szero();
    if (tid < 288){
      xw1a = *(const short8v*)&xwt[qd1*16];
      xw1b = *(const short8v*)&xwt[qd1*16 + 8];
    }
    // preload h_{t-1} fragments (shared across all pairs)
    short8v bh[7];
    #pragma unroll
    for (int ksi = 0; ksi < 7; ksi++){
      int k0 = ksi*32 + kg*8;
      bh[ksi] = (k0 < 200) ? *(const short8v*)&h_lds[q*200 + k0] : szero();
    }
    // 6 register pairs, 2 live accumulator chains
    #pragma unroll
    for (int jj = 0; jj < 6; jj += 2){
      f32x4 a0, a1;
      a0[0]=0.f; a0[1]=0.f; a0[2]=0.f; a0[3]=0.f; a1 = a0;
      #pragma unroll
      for (int ksi = 0; ksi < 7; ksi++){
        a0 = MFMA16(Bf[jj  ][ksi], bh[ksi], a0, 0,0,0);
        a1 = MFMA16(Bf[jj+1][ksi], bh[ksi], a1, 0,0,0);
      }
      #pragma unroll
      for (int s = 0; s < 2; s++){
        int p = wv + 8*(jj + s);
        int gt = p/13, nt = p - gt*13;
        int hu0 = nt*16 + kg*4;
        if (hu0 < 200){
          const f32x4& a = s ? a1 : a0;
          short4v g4;
          #pragma unroll
          for (int r = 0; r < 4; r++) g4[r] = (short)f2bf(a[r]);
          *(short4v*)&gates[(gt*16 + q)*200 + hu0] = g4;   // q = batch (D col)
        }
      }
    }
    // LDS-pool pair for waves 0..3 (one per SIMD)
    if (wv < 4){
      f32x4 a0;
      a0[0]=0.f; a0[1]=0.f; a0[2]=0.f; a0[3]=0.f;
      #pragma unroll
      for (int ksi = 0; ksi < 7; ksi++){
        short8v f = ((const short8v*)wpool)[(wv*7 + ksi)*64 + lane];
        a0 = MFMA16(f, bh[ksi], a0, 0,0,0);
      }
      int hu0 = (9 + wv)*16 + kg*4;
      if (hu0 < 200){
        short4v g4;
        #pragma unroll
        for (int r = 0; r < 4; r++) g4[r] = (short)f2bf(a0[r]);
        *(short4v*)&gates[(3*16 + q)*200 + hu0] = g4;
      }
    }
    __syncthreads();                                   // gates + xw ready
    // activation: quad = 4 consecutive hu of one b; all 4 gates in-lane
    {
      int base = bl0*200 + hu40*4;
      short4v gi4 = *(const short4v*)&gates[base];
      short4v gf4 = *(const short4v*)&gates[3200 + base];
      short4v gg4 = *(const short4v*)&gates[6400 + base];
      short4v go4 = *(const short4v*)&gates[9600 + base];
      short4v hp; f32x4 hw;
      #pragma unroll
      for (int r = 0; r < 4; r++){
        float gi = bf2f((u16)gi4[r]) + bf2f((u16)xw0a[r]);
        float gf = bf2f((u16)gf4[r]) + bf2f((u16)xw0a[4+r]);
        float gg = bf2f((u16)gg4[r]) + bf2f((u16)xw0b[r]);
        float go = bf2f((u16)go4[r]) + bf2f((u16)xw0b[4+r]);
        float c = sigm(gf)*cst[r] + sigm(gi)*tanh_u(gg);
        cst[r] = c;
        float hv = sigm(go)*tanh_u(c);
        hp[r] = (short)f2bf(hv); hw[r] = hv;
      }
      *(short4v*)&h_lds[base] = hp;
      int gb = grp*16 + bl0;
      if (dir == 0){
        *(f32x4*)&h_ws[((size_t)gb*256 + t)*400 + hu40*4] = hw;
      } else {
        int tp = Ls[bl0] - 1 - t;
        if (tp >= 0) *(f32x4*)&h_ws[((size_t)gb*256 + tp)*400 + 200 + hu40*4] = hw;
      }
    }
    if (tid < 288){
      int base = bl1*200 + hu41*4;
      short4v gi4 = *(const short4v*)&gates[base];
      short4v gf4 = *(const short4v*)&gates[3200 + base];
      short4v gg4 = *(const short4v*)&gates[6400 + base];
      short4v go4 = *(const short4v*)&gates[9600 + base];
      short4v hp; f32x4 hw;
      #pragma unroll
      for (int r = 0; r < 4; r++){
        float gi = bf2f((u16)gi4[r]) + bf2f((u16)xw1a[r]);
        float gf = bf2f((u16)gf4[r]) + bf2f((u16)xw1a[4+r]);
        float gg = bf2f((u16)gg4[r]) + bf2f((u16)xw1b[r]);
        float go = bf2f((u16)go4[r]) + bf2f((u16)xw1b[4+r]);
        float c = sigm(gf)*cst[4+r] + sigm(gi)*tanh_u(gg);
        cst[4+r] = c;
        float hv = sigm(go)*tanh_u(c);
        hp[r] = (short)f2bf(hv); hw[r] = hv;
      }
      *(short4v*)&h_lds[base] = hp;
      int gb = grp*16 + bl1;
      if (dir == 0){
        *(f32x4*)&h_ws[((size_t)gb*256 + t)*400 + hu41*4] = hw;
      } else {
        int tp = Ls[bl1] - 1 - t;
        if (tp >= 0) *(f32x4*)&h_ws[((size_t)gb*256 + tp)*400 + 200 + hu41*4] = hw;
      }
    }
    __syncthreads();                                   // h_lds ready for t+1
  }
}

// ---------------- K4b: fill bwd rows t>=L with h_bwd_r[0] (== stored row L-1) ----------------
__global__ void k4b_fill(const int* __restrict__ seq, float* __restrict__ h_ws){
  const int b = blockIdx.x;
  const int L = seq[b];
  const int cnt = (256 - L)*200;
  const float* src = h_ws + ((size_t)b*256 + (L-1))*400 + 200;
  for (int i = threadIdx.x; i < cnt; i += 256){
    int tt = L + i/200, cc = i - (i/200)*200;
    h_ws[((size_t)b*256 + tt)*400 + 200 + cc] = src[cc];
  }
}

// ---------------- K5: causal growing-window attention (query term cancels) ----------------
__launch_bounds__(512)
__global__ void k5_attn(const float* __restrict__ h_ws, const float* __restrict__ wattn,
                        float* __restrict__ x1_att){
  __shared__ float a_lds[256];
  const int tid = threadIdx.x;
  const int b = blockIdx.x;
  const int lane = tid & 63, wv = tid >> 6;
  for (int row = wv*32; row < wv*32 + 32; row++){
    float s = 0.f;
    for (int j = lane; j < 400; j += 64)
      s += h_ws[((size_t)b*256 + row)*400 + j] * wattn[j];
    #pragma unroll
    for (int m = 32; m > 0; m >>= 1) s += __shfl_xor(s, m, 64);
    if (lane == 0) a_lds[row] = s;
  }
  __syncthreads();
  const int col = tid;
  const bool act = col < 400;
  float m = -1e30f, den = 0.f, num = 0.f;
  const float* hb = h_ws + (size_t)b*256*400 + col;
  float* ob = x1_att + (size_t)b*256*400 + col;
  float hvA = act ? hb[0] : 0.f;
  float hvB = act ? hb[400] : 0.f;
  for (int t = 0; t < 256; t++){
    float hv = hvA; hvA = hvB;
    hvB = (act && t + 2 < 256) ? hb[(size_t)(t+2)*400] : 0.f;
    float at = a_lds[t];
    float mn = fmaxf(m, at);
    float rr  = __expf(m - mn);
    float wgt = __expf(at - mn);
    den = den*rr + wgt;
    num = num*rr + wgt*hv;
    m = mn;
    if (act) ob[(size_t)t*400] = num/den;
  }
}

// ---------------- K6: out = [x1_att ; x2p] @ w_mlp^T + b, masked, f32 ----------------
__global__ void k6_out(const float* __restrict__ x1_att, const float* __restrict__ x2p,
                       const float* __restrict__ wmlp, const float* __restrict__ bmlp,
                       const int* __restrict__ seq, float* __restrict__ out){
  __shared__ float rows[8*800];
  const int tid = threadIdx.x;
  const size_t n0 = (size_t)blockIdx.x*8;
  const int b = (int)(n0 >> 8), t0 = (int)(n0 & 255);
  const int L = seq[b];
  for (int i = tid; i < 3200; i += 256){
    int r = i / 400, e = i - r*400;
    rows[r*800 + e]       = x1_att[(n0 + r)*400 + e];
    rows[r*800 + 400 + e] = x2p  [(n0 + r)*400 + e];
  }
  __syncthreads();
  for (int e = tid; e < 400; e += 256){
    float bv = bmlp[e];
    float acc[8];
    #pragma unroll
    for (int r = 0; r < 8; r++) acc[r] = bv;
    const float* wr = wmlp + (size_t)e*800;
    for (int j = 0; j < 800; j += 4){
      const f32x4 w4 = *(const f32x4*)&wr[j];
      #pragma unroll
      for (int r = 0; r < 8; r++){
        const f32x4 x4 = *(const f32x4*)&rows[r*800 + j];
        acc[r] += x4[0]*w4[0] + x4[1]*w4[1] + x4[2]*w4[2] + x4[3]*w4[3];
      }
    }
    #pragma unroll
    for (int r = 0; r < 8; r++){
      float v = (t0 + r < L) ? acc[r] : 0.f;
      out[(n0 + r)*400 + e] = v;
    }
  }
}

extern "C" void kernel_launch(void* const* d_in, const int* in_sizes, int n_in,
                              void* d_out, int out_size, void* d_ws, size_t ws_size,
                              hipStream_t stream){
  const float* x1   = (const float*)d_in[0];
  const float* x2   = (const float*)d_in[1];
  // d_in[2] = cate: unused by the reference
  const int*   seq  = (const int*)d_in[3];
  const float* wihf = (const float*)d_in[4];
  const float* whhf = (const float*)d_in[5];
  const float* bihf = (const float*)d_in[6];
  const float* bhhf = (const float*)d_in[7];
  const float* wihb = (const float*)d_in[8];
  const float* whhb = (const float*)d_in[9];
  const float* bihb = (const float*)d_in[10];
  const float* bhhb = (const float*)d_in[11];
  const float* wq   = (const float*)d_in[12];
  const float* bq   = (const float*)d_in[13];
  const float* wk   = (const float*)d_in[14];
  const float* bk   = (const float*)d_in[15];
  const float* wmha = (const float*)d_in[16];
  const float* bmha = (const float*)d_in[17];
  const float* wattn= (const float*)d_in[18];
  // d_in[19] = b_attn: cancels in softmax
  const float* wmlp = (const float*)d_in[20];
  const float* bmlp = (const float*)d_in[21];
  float* out = (float*)d_out;

  char* ws = (char*)d_ws;
  u16*  wqb    = (u16*)(ws + 0);              // 320,000 B
  u16*  wkb    = (u16*)(ws + 320000);         // 320,000
  u16*  wihfb  = (u16*)(ws + 640000);         // 640,000
  u16*  wihbb  = (u16*)(ws + 1280000);        // 640,000
  u16*  whhfb  = (u16*)(ws + 1920000);        // 320,000
  u16*  whhbb  = (u16*)(ws + 2240000);        // 320,000
  float* bgf   = (float*)(ws + 2560000);      // 3,200 (pad 4,096)
  float* bgb   = (float*)(ws + 2564096);      // 3,200 (pad 4,096)
  float* pooled= (float*)(ws + 2568192);      // 13,107,200
  float* x2p   = (float*)(ws + 15675392);     // 13,107,200
  u16*  xWf    = (u16*)(ws + 28782592);       // 13,107,200
  u16*  xWb    = (u16*)(ws + 41889792);       // 13,107,200
  float* h_ws  = (float*)(ws + 54996992);     // 13,107,200 (end ~68.1MB)
  float* x1_att= (float*)(ws + 28782592);     // overlay: xWf dead after k4

  k0_cvt  <<<dim3(1250), dim3(256), 0, stream>>>(wq, wk, wihf, wihb, whhf, whhb,
                                                 bihf, bhhf, bihb, bhhb,
                                                 wqb, wkb, wihfb, wihbb, whhfb, whhbb, bgf, bgb);
  k1_pool <<<dim3(4096), dim3(256), 0, stream>>>(x2, wqb, bq, wkb, bk, pooled);
  k3_xw   <<<dim3(256),  dim3(512), 0, stream>>>(x1, seq, wihfb, wihbb, bgf, bgb, xWf, xWb);
  k2_x2p  <<<dim3(1024), dim3(256), 0, stream>>>(pooled, wmha, bmha, x2p);
  k4_lstm <<<dim3(4),    dim3(512), 0, stream>>>(xWf, xWb, whhfb, whhbb, seq, h_ws);
  k4b_fill<<<dim3(32),   dim3(256), 0, stream>>>(seq, h_ws);
  k5_attn <<<dim3(32),   dim3(512), 0, stream>>>(h_ws, wattn, x1_att);
  k6_out  <<<dim3(1024), dim3(256), 0, stream>>>(x1_att, x2p, wmlp, bmlp, seq, out);
}